// Round 19
// baseline (247.216 us; speedup 1.0000x reference)
//
#include <hip/hip_runtime.h>
#include <hip/hip_bf16.h>

typedef unsigned short u16;
typedef __attribute__((ext_vector_type(8))) short bf16x8;
typedef __attribute__((ext_vector_type(4))) float f32x4;

#define D_DIM 1024
#define F_DIM 2048
#define E_NUM 8
#define EPS_RMS 1.1920929e-07f
#define NCHUNK 16

__device__ __forceinline__ u16 f2bf(float f) {
  union { float f; unsigned u; } v; v.f = f;
  unsigned r = v.u + 0x7FFFu + ((v.u >> 16) & 1u);   // RNE
  return (u16)(r >> 16);
}

__device__ __forceinline__ void async16(const void* g, void* l) {
  __builtin_amdgcn_global_load_lds((const __attribute__((address_space(1))) void*)g,
                                   (__attribute__((address_space(3))) void*)l, 16, 0, 0);
}

// ---------------- prep: fused {W1+W2 -> Wc, W3 -> W3t, gate}, WRITE-CONTIGUOUS tiles ----------------
// Diagnosis r18: prep paced by HBM writes at 1.07 TB/s (256B slivers across 2KB rows -> DRAM page
// thrash). Fix: each block produces FULL output rows.
//   W1/W2 block: [32 f-cols][1024 d] -> 32 complete adjacent 2KB Wc rows (64KB contiguous).
//   W3 block:    [32 d-rows][1024 f-half] -> 32 contiguous 2KB row-halves.
// Transpose via u16 LDS [32][1026] (pad -> <=2-way write conflicts). 512 threads.
// blocks [0,1024): W1/W2 ; [1024,1536): W3 ; [1536,1536+T): gate (512-thread variant).
__global__ __launch_bounds__(512) void prep_kernel(
    const float* __restrict__ W1, const float* __restrict__ W2,
    const float* __restrict__ W3, const float* __restrict__ scale,
    const float* __restrict__ x, const float* __restrict__ Wg,
    u16* __restrict__ Wc, u16* __restrict__ W3t, u16* __restrict__ xh,
    int* __restrict__ topi, float* __restrict__ gatev)
{
  __shared__ u16 lbuf[32][1026];     // 65.7 KB
  __shared__ float red[8][9];
  __shared__ float invs;
  const int lin = blockIdx.x;
  const int tid = threadIdx.x;

  if (lin < 1024) {
    // ---- W1/W2: tile [32 f][1024 d] ----
    const int z = lin >> 6;              // 0..15: [0,8)=W1, [8,16)=W2
    const int fb = (lin & 63) * 32;      // f base
    const int e = z & 7;
    const float* W = (z < 8) ? W1 : W2;
    const int gofs = (z < 8) ? 0 : 16;
    const float* Wp = W + (size_t)e * D_DIM * F_DIM;
    const int fq = tid & 7;              // 4-float group within 32 f
#pragma unroll
    for (int it = 0; it < 16; ++it) {
      const int d = it * 64 + (tid >> 3);
      const float4 v = *reinterpret_cast<const float4*>(Wp + (size_t)d * F_DIM + fb + fq * 4);
      const float s = scale[(size_t)e * D_DIM + d];
      lbuf[fq*4+0][d] = f2bf(v.x * s);
      lbuf[fq*4+1][d] = f2bf(v.y * s);
      lbuf[fq*4+2][d] = f2bf(v.z * s);
      lbuf[fq*4+3][d] = f2bf(v.w * s);
    }
    __syncthreads();
    u16* op = Wc + (size_t)e * (2*F_DIM) * D_DIM;
#pragma unroll
    for (int it = 0; it < 8; ++it) {
      const int idx = it * 512 + tid;    // 4096 chunks = 32 rows x 128 x 16B
      const int r = idx >> 7;            // 0..31 (f within tile)
      const int c = idx & 127;
      const int rphys = ((fb + r) >> 4) * 32 + (r & 15) + gofs;
      *reinterpret_cast<int4*>(op + (size_t)rphys * D_DIM + c * 8) =
          *reinterpret_cast<const int4*>(&lbuf[r][c * 8]);
    }
  } else if (lin < 1536) {
    // ---- W3: tile [32 d][1024 f-half] ----
    const int l2 = lin - 1024;
    const int e = l2 >> 6;               // 0..7
    const int rem = l2 & 63;
    const int db = (rem >> 1) * 32;      // d base
    const int fhb = (rem & 1) * 1024;    // f-half base
    const float* Wp = W3 + (size_t)e * F_DIM * D_DIM;
    const int dq = tid & 7;
#pragma unroll
    for (int it = 0; it < 16; ++it) {
      const int f = it * 64 + (tid >> 3);
      const float4 v = *reinterpret_cast<const float4*>(Wp + (size_t)(fhb + f) * D_DIM + db + dq * 4);
      lbuf[dq*4+0][f] = f2bf(v.x);
      lbuf[dq*4+1][f] = f2bf(v.y);
      lbuf[dq*4+2][f] = f2bf(v.z);
      lbuf[dq*4+3][f] = f2bf(v.w);
    }
    __syncthreads();
    u16* op = W3t + (size_t)e * D_DIM * F_DIM;
#pragma unroll
    for (int it = 0; it < 8; ++it) {
      const int idx = it * 512 + tid;
      const int r = idx >> 7;            // 0..31 (d within tile)
      const int c = idx & 127;
      *reinterpret_cast<int4*>(op + (size_t)(db + r) * F_DIM + fhb + c * 8) =
          *reinterpret_cast<const int4*>(&lbuf[r][c * 8]);
    }
  } else {
    // ---- gate (512 threads: float2 per thread) ----
    const int t = lin - 1536;
    const float2 xv = reinterpret_cast<const float2*>(x + (size_t)t * D_DIM)[tid];
    float ss = xv.x*xv.x + xv.y*xv.y;
    float s[8];
#pragma unroll
    for (int e = 0; e < 8; ++e) s[e] = 0.f;
    const float xa[2] = {xv.x, xv.y};
#pragma unroll
    for (int j = 0; j < 2; ++j) {
      const float4* wr = reinterpret_cast<const float4*>(Wg + (size_t)(tid*2 + j) * 8);
      float4 w0 = wr[0], w1 = wr[1];
      s[0] += xa[j]*w0.x; s[1] += xa[j]*w0.y; s[2] += xa[j]*w0.z; s[3] += xa[j]*w0.w;
      s[4] += xa[j]*w1.x; s[5] += xa[j]*w1.y; s[6] += xa[j]*w1.z; s[7] += xa[j]*w1.w;
    }
#pragma unroll
    for (int off = 32; off > 0; off >>= 1) {
      ss += __shfl_down(ss, off);
#pragma unroll
      for (int e = 0; e < 8; ++e) s[e] += __shfl_down(s[e], off);
    }
    const int wv = tid >> 6, lane = tid & 63;
    if (lane == 0) { red[wv][8] = ss;
#pragma unroll
      for (int e = 0; e < 8; ++e) red[wv][e] = s[e]; }
    __syncthreads();
    if (tid == 0) {
      float sum2 = 0.f;
#pragma unroll
      for (int w = 0; w < 8; ++w) sum2 += red[w][8];
      invs = rsqrtf(sum2 * (1.0f / D_DIM) + EPS_RMS);
      float sc[8];
#pragma unroll
      for (int e = 0; e < 8; ++e) {
        sc[e] = 0.f;
#pragma unroll
        for (int w = 0; w < 8; ++w) sc[e] += red[w][e];
      }
      int i0 = 0; float v0 = sc[0];
#pragma unroll
      for (int e = 1; e < 8; ++e) if (sc[e] > v0) { v0 = sc[e]; i0 = e; }
      int i1 = -1; float v1 = -3.0e38f;
#pragma unroll
      for (int e = 0; e < 8; ++e) if (e != i0 && sc[e] > v1) { v1 = sc[e]; i1 = e; }
      float p1 = 1.0f / (1.0f + expf(v0 - v1));
      float p0 = 1.0f - p1;
      topi[2*t] = i0; topi[2*t+1] = i1;
      gatev[2*t] = p0; gatev[2*t+1] = p1;
    }
    __syncthreads();
    const float inv = invs;
    ushort2 o;
    o.x = f2bf(xv.x*inv); o.y = f2bf(xv.y*inv);
    reinterpret_cast<ushort2*>(xh + (size_t)t * D_DIM)[tid] = o;
  }
}

// ---------------- count: per-chunk register histogram (no atomics) ----------------
__global__ __launch_bounds__(256) void count_kernel(
    const int* __restrict__ topi, int* __restrict__ percnt, int nent)
{
  const int blk = blockIdx.x;
  const int tid = threadIdx.x;
  const int per = (nent + NCHUNK*256 - 1) / (NCHUNK*256);
  const int cbase = blk * 256 * per;
  int c[8];
#pragma unroll
  for (int q = 0; q < 8; ++q) c[q] = 0;
  for (int i = 0; i < per; ++i) {
    const int idx = cbase + tid * per + i;
    if (idx < nent) {
      const int e = topi[idx];
#pragma unroll
      for (int q = 0; q < 8; ++q) c[q] += (e == q) ? 1 : 0;
    }
  }
#pragma unroll
  for (int off = 32; off > 0; off >>= 1)
#pragma unroll
    for (int q = 0; q < 8; ++q) c[q] += __shfl_down(c[q], off);
  __shared__ int red[4][8];
  const int wv = tid >> 6, lane = tid & 63;
  if (lane == 0)
#pragma unroll
    for (int q = 0; q < 8; ++q) red[wv][q] = c[q];
  __syncthreads();
  if (tid < 8) percnt[blk * 8 + tid] = red[0][tid] + red[1][tid] + red[2][tid] + red[3][tid];
}

// ---------------- scatter (scan folded in): chunk-local LDS cursors ----------------
__global__ __launch_bounds__(256) void scatter_kernel(
    const int* __restrict__ topi, const int* __restrict__ percnt,
    int* __restrict__ rowtok, int* __restrict__ slots, int* __restrict__ offs, int nent)
{
  __shared__ int cur[8];
  const int blk = blockIdx.x, tid = threadIdx.x;
  if (tid == 0) {
    int tot[8];
#pragma unroll
    for (int e = 0; e < 8; ++e) {
      tot[e] = 0;
      for (int c = 0; c < NCHUNK; ++c) tot[e] += percnt[c*8 + e];
    }
    int acc = 0, start[8];
#pragma unroll
    for (int e = 0; e < 8; ++e) {
      start[e] = acc;
      if (blk == 0) offs[e] = acc;
      acc += (tot[e] + 255) & ~255;
    }
    if (blk == 0) offs[8] = acc;
    for (int c = 0; c < blk; ++c)
#pragma unroll
      for (int e = 0; e < 8; ++e) start[e] += percnt[c*8 + e];
#pragma unroll
    for (int e = 0; e < 8; ++e) cur[e] = start[e];
  }
  __syncthreads();
  const int per = (nent + NCHUNK*256 - 1) / (NCHUNK*256);
  const int cbase = blk * 256 * per;
  for (int i = 0; i < per; ++i) {
    const int idx = cbase + tid * per + i;
    if (idx < nent) {
      const int e = topi[idx];
      const int pos = atomicAdd(&cur[e], 1);
      rowtok[pos] = idx >> 1;
      slots[idx] = pos;
    }
  }
}

// ---------------- FFN1: round-11 ring (unchanged) ----------------
__global__ __launch_bounds__(512, 4) void ffn1_kernel(
    const u16* __restrict__ xh, const u16* __restrict__ Wc,
    const float* __restrict__ b1, const float* __restrict__ b2,
    const int* __restrict__ rowtok, const int* __restrict__ offs,
    u16* __restrict__ h)
{
  __shared__ __align__(16) u16 smem[36864];   // 72 KB: buf b at b*12288; A +0, B +8192

  const int row0 = blockIdx.y * 256;
  if (row0 >= offs[8]) return;
  int e = 0;
#pragma unroll
  for (int i = 1; i < 8; ++i) e += (row0 >= offs[i]) ? 1 : 0;

  const int bx = blockIdx.x;
  const int n0p = bx * 128;
  const int tid = threadIdx.x;
  const int lane = tid & 63;
  const int l15 = lane & 15;
  const int wv = tid >> 6;
  const int wm = wv >> 1;
  const int wn = wv & 1;

  int arow[2];
  const u16* gAp[2];
#pragma unroll
  for (int j = 0; j < 2; ++j) {
    const int i = tid + 512*j;
    const int p = i >> 3;
    const int v = (i & 7) ^ (p & 7);
    arow[j] = 2*p + (v >> 2);
    int tk = rowtok[row0 + arow[j]];
    if (tk < 0) tk = 0;
    gAp[j] = xh + (size_t)tk * D_DIM + (v & 3) * 8;
  }
  const u16* gBp;
  {
    const int i = tid;
    const int p = i >> 3;
    const int v = (i & 7) ^ (p & 7);
    const int brow = 2*p + (v >> 2);
    gBp = Wc + ((size_t)e * (2*F_DIM) + n0p + brow) * D_DIM + (v & 3) * 8;
  }

  const f32x4 zero = {0.f, 0.f, 0.f, 0.f};
  f32x4 acc[4][4];
#pragma unroll
  for (int i = 0; i < 4; ++i)
#pragma unroll
    for (int j = 0; j < 4; ++j) acc[i][j] = zero;

  const int rlane = (((l15 & 1) << 2) + (lane >> 4)) ^ (l15 >> 1);
  const int aoff = (l15 >> 1) * 64 + rlane * 8;
  const int boff = (l15 >> 1) * 64 + rlane * 8;

#define STAGE1(b, k0)                                                       \
  {                                                                         \
    const int base_ = (b) * 12288;                                          \
    async16(gAp[0] + (k0), &smem[base_ + tid*8]);                           \
    async16(gAp[1] + (k0), &smem[base_ + (tid + 512)*8]);                   \
    async16(gBp   + (k0), &smem[base_ + 8192 + tid*8]);                     \
  }

  STAGE1(0, 0);
  STAGE1(1, 32);

  const int NSTEP = D_DIM / 32;
  for (int t = 0; t < NSTEP; ++t) {
    const int bsel = t % 3;
    if (t + 1 < NSTEP) {
      asm volatile("s_waitcnt vmcnt(3)" ::: "memory");
    } else {
      asm volatile("s_waitcnt vmcnt(0)" ::: "memory");
    }
    __builtin_amdgcn_s_barrier();
    if (t + 2 < NSTEP) {
      const int bn = (t + 2) % 3;
      const int kn = (t + 2) * 32;
      STAGE1(bn, kn);
    }
    const int aB = bsel * 12288, bB = aB + 8192;
    bf16x8 af[4], bv[4];
#pragma unroll
    for (int mi = 0; mi < 4; ++mi)
      af[mi] = *(const bf16x8*)(&smem[aB + (wm*32 + mi*8)*64 + aoff]);
#pragma unroll
    for (int ni = 0; ni < 4; ++ni)
      bv[ni] = *(const bf16x8*)(&smem[bB + (wn*32 + ni*8)*64 + boff]);
#pragma unroll
    for (int mi = 0; mi < 4; ++mi)
#pragma unroll
      for (int ni = 0; ni < 4; ++ni)
        acc[mi][ni] = __builtin_amdgcn_mfma_f32_16x16x32_bf16(af[mi], bv[ni], acc[mi][ni], 0, 0, 0);
  }
#undef STAGE1

#pragma unroll
  for (int mi = 0; mi < 4; ++mi) {
    const int rbase = row0 + wm*64 + mi*16 + (lane >> 4)*4;
#pragma unroll
    for (int q = 0; q < 2; ++q) {
      const int rc = bx*64 + wn*32 + q*16 + l15;
      const float bb1 = b1[e*F_DIM + rc], bb2 = b2[e*F_DIM + rc];
#pragma unroll
      for (int r = 0; r < 4; ++r) {
        float a = acc[mi][2*q][r] + bb1;
        float g = acc[mi][2*q+1][r] + bb2;
        h[(size_t)(rbase + r) * F_DIM + rc] = f2bf(a / (1.f + __expf(-a)) * g);
      }
    }
  }
}

// ---------------- FFN2: round-15 version (2-buf, BK=64, XOR swizzle, XCD chunking) ----------------
__global__ __launch_bounds__(256, 2) void ffn2_kernel(
    const u16* __restrict__ h, const u16* __restrict__ W3t,
    const float* __restrict__ b3, const int* __restrict__ offs,
    float* __restrict__ opart)
{
  __shared__ __align__(16) u16 smem[32768];

  const int lin = blockIdx.y * gridDim.x + blockIdx.x;
  const int qc  = (gridDim.x * gridDim.y) >> 3;
  const int L   = (lin & 7) * qc + (lin >> 3);
  const int bx  = L % gridDim.x;
  const int by  = L / gridDim.x;

  const int row0 = by * 128;
  if (row0 >= offs[8]) return;
  int e = 0;
#pragma unroll
  for (int i = 1; i < 8; ++i) e += (row0 >= offs[i]) ? 1 : 0;

  const int n0 = bx * 128;
  const int tid = threadIdx.x;
  const int lane = tid & 63;
  const int wv = tid >> 6;
  const int wm = wv >> 1;
  const int wn = wv & 1;

  const int srow = tid >> 3;
  const int sseg = (tid & 7) ^ (srow & 7);
  const u16* gA[4]; const u16* gB[4];
#pragma unroll
  for (int j = 0; j < 4; ++j) {
    gA[j] = h   + (size_t)(row0 + srow + 32*j) * F_DIM + sseg * 8;
    gB[j] = W3t + ((size_t)e * D_DIM + n0 + srow + 32*j) * F_DIM + sseg * 8;
  }

  const f32x4 zero = {0.f, 0.f, 0.f, 0.f};
  f32x4 acc[4][4];
#pragma unroll
  for (int i = 0; i < 4; ++i)
#pragma unroll
    for (int j = 0; j < 4; ++j) acc[i][j] = zero;

  const int rswz = (lane & 7) << 3;
  const int kpart = (lane >> 4) * 8;
  const int arowbase = (wm*64 + (lane & 15)) * 64;
  const int browbase = (wn*64 + (lane & 15)) * 64;

#define STAGE2(b, k0)                                                       \
  {                                                                         \
    const int aB_ = (b)*8192, bB_ = 16384 + (b)*8192;                       \
    _Pragma("unroll")                                                       \
    for (int j = 0; j < 4; ++j) {                                           \
      async16(gA[j] + (k0), &smem[aB_ + (tid + 256*j)*8]);                  \
      async16(gB[j] + (k0), &smem[bB_ + (tid + 256*j)*8]);                  \
    }                                                                       \
  }

  STAGE2(0, 0);
  __syncthreads();

  int cur = 0;
  for (int t = 0; t < F_DIM/64; ++t) {
    if (t + 1 < F_DIM/64) STAGE2(cur ^ 1, (t+1)*64);
    const int aB = cur*8192, bB = 16384 + cur*8192;
#pragma unroll
    for (int kk = 0; kk < 2; ++kk) {
      const int ko = kk*32 + kpart;
      bf16x8 af[4], bv[4];
#pragma unroll
      for (int mi = 0; mi < 4; ++mi)
        af[mi] = *(const bf16x8*)(&smem[aB + ((arowbase + mi*1024 + ko) ^ rswz)]);
#pragma unroll
      for (int ni = 0; ni < 4; ++ni)
        bv[ni] = *(const bf16x8*)(&smem[bB + ((browbase + ni*1024 + ko) ^ rswz)]);
#pragma unroll
      for (int mi = 0; mi < 4; ++mi)
#pragma unroll
        for (int ni = 0; ni < 4; ++ni)
          acc[mi][ni] = __builtin_amdgcn_mfma_f32_16x16x32_bf16(af[mi], bv[ni], acc[mi][ni], 0, 0, 0);
    }
    __syncthreads();
    cur ^= 1;
  }
#undef STAGE2

#pragma unroll
  for (int mi = 0; mi < 4; ++mi) {
    const int rbase = row0 + wm*64 + mi*16 + (lane >> 4)*4;
#pragma unroll
    for (int ni = 0; ni < 4; ++ni) {
      const int gc = n0 + wn*64 + ni*16 + (lane & 15);
      const float bb = b3[e*D_DIM + gc];
#pragma unroll
      for (int r = 0; r < 4; ++r)
        opart[(size_t)(rbase + r) * D_DIM + gc] = acc[mi][ni][r] + bb;
    }
  }
}

// ---------------- combine: y[t] = w0*opart[s0] + w1*opart[s1] ----------------
__global__ __launch_bounds__(256) void combine_kernel(
    const float* __restrict__ opart, const int* __restrict__ slots,
    const float* __restrict__ gatev, float* __restrict__ y)
{
  const int t = blockIdx.x;
  const int s0 = slots[2*t], s1 = slots[2*t+1];
  const float w0 = gatev[2*t], w1 = gatev[2*t+1];
  const float4 a = reinterpret_cast<const float4*>(opart + (size_t)s0 * D_DIM)[threadIdx.x];
  const float4 b = reinterpret_cast<const float4*>(opart + (size_t)s1 * D_DIM)[threadIdx.x];
  float4 o;
  o.x = w0*a.x + w1*b.x; o.y = w0*a.y + w1*b.y;
  o.z = w0*a.z + w1*b.z; o.w = w0*a.w + w1*b.w;
  reinterpret_cast<float4*>(y + (size_t)t * D_DIM)[threadIdx.x] = o;
}

extern "C" void kernel_launch(void* const* d_in, const int* in_sizes, int n_in,
                              void* d_out, int out_size, void* d_ws, size_t ws_size,
                              hipStream_t stream)
{
  const float* x  = (const float*)d_in[0];
  const float* Wg = (const float*)d_in[1];
  const float* nw = (const float*)d_in[2];
  const float* W1 = (const float*)d_in[3];
  const float* b1 = (const float*)d_in[4];
  const float* W2 = (const float*)d_in[5];
  const float* b2 = (const float*)d_in[6];
  const float* W3 = (const float*)d_in[7];
  const float* b3 = (const float*)d_in[8];
  float* y = (float*)d_out;

  const int T = in_sizes[0] / D_DIM;           // 4096
  const int NENT = T * 2;
  const int RCAP = ((NENT + E_NUM * 255) + 255) & ~255;
  const int MT1 = RCAP / 256;                  // 40
  const int MT2 = RCAP / 128;                  // 80

  char* ws = (char*)d_ws;
  size_t off_ = 0;
  auto take = [&](size_t bytes) { char* p = ws + off_; off_ = (off_ + bytes + 255) & ~(size_t)255; return p; };
  u16* Wc     = (u16*)take((size_t)E_NUM * 2 * F_DIM * D_DIM * 2); // 64 MB } opart aliases
  u16* W3t    = (u16*)take((size_t)E_NUM * D_DIM * F_DIM * 2);     // 16 MB
  u16* xh     = (u16*)take((size_t)T * D_DIM * 2);
  u16* hbuf   = (u16*)take((size_t)RCAP * F_DIM * 2);              // 40 MB
  int* rowtok = (int*)take((size_t)RCAP * 4);
  int* slots  = (int*)take((size_t)NENT * 4);
  int* topi   = (int*)take((size_t)NENT * 4);
  float* gatev= (float*)take((size_t)NENT * 4);
  int* percnt = (int*)take(NCHUNK * 8 * 4);
  int* offs   = (int*)take(64);
  float* opart = (float*)Wc;   // overlaps Wc (dead after ffn1)
  (void)ws_size; (void)n_in; (void)out_size;

  (void)hipMemsetAsync(rowtok, 0xFF, (size_t)RCAP * 4, stream);

  prep_kernel<<<1536 + T, 512, 0, stream>>>(W1, W2, W3, nw, x, Wg, Wc, W3t, xh, topi, gatev);
  count_kernel<<<NCHUNK, 256, 0, stream>>>(topi, percnt, NENT);
  scatter_kernel<<<NCHUNK, 256, 0, stream>>>(topi, percnt, rowtok, slots, offs, NENT);

  ffn1_kernel<<<dim3((2*F_DIM)/128, MT1), 512, 0, stream>>>(xh, Wc, b1, b2, rowtok, offs, hbuf);
  ffn2_kernel<<<dim3(D_DIM/128, MT2), 256, 0, stream>>>(hbuf, W3t, b3, offs, opart);
  combine_kernel<<<T, 256, 0, stream>>>(opart, slots, gatev, y);
}

// Round 20
// 224.023 us; speedup vs baseline: 1.1035x; 1.1035x over previous
//
#include <hip/hip_runtime.h>
#include <hip/hip_bf16.h>

typedef unsigned short u16;
typedef __attribute__((ext_vector_type(8))) short bf16x8;
typedef __attribute__((ext_vector_type(4))) float f32x4;

#define D_DIM 1024
#define F_DIM 2048
#define E_NUM 8
#define EPS_RMS 1.1920929e-07f
#define NCHUNK 16

__device__ __forceinline__ u16 f2bf(float f) {
  union { float f; unsigned u; } v; v.f = f;
  unsigned r = v.u + 0x7FFFu + ((v.u >> 16) & 1u);   // RNE
  return (u16)(r >> 16);
}

__device__ __forceinline__ void async16(const void* g, void* l) {
  __builtin_amdgcn_global_load_lds((const __attribute__((address_space(1))) void*)g,
                                   (__attribute__((address_space(3))) void*)l, 16, 0, 0);
}

// ---------------- prep: {W1+W2 transpose->Wc, gate} (round-15 proven form; W3 moved into ffn1 grid) ----------------
// blocks [0,8192): Wc[e] 2F rows: W1 col c -> row (c>>4)*32+(c&15); W2 -> +16. norm_w folded.
// blocks [8192,8192+T): gate -> xh bf16, topi, gatev.
__global__ __launch_bounds__(256) void prep_kernel(
    const float* __restrict__ W1, const float* __restrict__ W2,
    const float* __restrict__ scale,
    const float* __restrict__ x, const float* __restrict__ Wg,
    u16* __restrict__ Wc, u16* __restrict__ xh,
    int* __restrict__ topi, float* __restrict__ gatev)
{
  __shared__ float tile[64][65];
  __shared__ float red[4][9];
  __shared__ float invs;
  const int lin = blockIdx.x;
  const int tid = threadIdx.x;

  if (lin < 8192) {
    const int z = lin >> 9;              // 0..15
    const int rem = lin & 511;
    const int cb = (rem & 31) * 64;      // F cols
    const int rb = (rem >> 5) * 64;      // D rows
    const int e = z & 7;
    const float* W = (z < 8) ? W1 : W2;
    const int gofs = (z < 8) ? 0 : 16;
    const int tx = tid & 15, ty = tid >> 4;
    const float* Wp = W + (size_t)e * D_DIM * F_DIM;
#pragma unroll
    for (int rep = 0; rep < 4; ++rep) {
      const int i = ty + rep * 16;
      float4 v = *reinterpret_cast<const float4*>(Wp + (size_t)(rb + i) * F_DIM + cb + tx * 4);
      tile[i][tx*4+0] = v.x; tile[i][tx*4+1] = v.y; tile[i][tx*4+2] = v.z; tile[i][tx*4+3] = v.w;
    }
    __syncthreads();
    float sc[4];
#pragma unroll
    for (int q = 0; q < 4; ++q) sc[q] = scale[(size_t)e * D_DIM + rb + tx*4 + q];
    u16* op = Wc + (size_t)e * (2*F_DIM) * D_DIM;
#pragma unroll
    for (int rep = 0; rep < 4; ++rep) {
      const int j = ty + rep * 16;
      const int c = cb + j;
      const int rphys = ((c >> 4) << 5) + (c & 15) + gofs;
      ushort4 o;
      o.x = f2bf(tile[tx*4+0][j] * sc[0]);
      o.y = f2bf(tile[tx*4+1][j] * sc[1]);
      o.z = f2bf(tile[tx*4+2][j] * sc[2]);
      o.w = f2bf(tile[tx*4+3][j] * sc[3]);
      *reinterpret_cast<ushort4*>(op + (size_t)rphys * D_DIM + rb + tx*4) = o;
    }
  } else {
    // ---- gate ----
    const int t = lin - 8192;
    const float4 xv = reinterpret_cast<const float4*>(x + (size_t)t * D_DIM)[tid];
    float ss = xv.x*xv.x + xv.y*xv.y + xv.z*xv.z + xv.w*xv.w;
    float s[8];
#pragma unroll
    for (int e = 0; e < 8; ++e) s[e] = 0.f;
    const float xa[4] = {xv.x, xv.y, xv.z, xv.w};
#pragma unroll
    for (int j = 0; j < 4; ++j) {
      const float4* wr = reinterpret_cast<const float4*>(Wg + (size_t)(tid*4 + j) * 8);
      float4 w0 = wr[0], w1 = wr[1];
      s[0] += xa[j]*w0.x; s[1] += xa[j]*w0.y; s[2] += xa[j]*w0.z; s[3] += xa[j]*w0.w;
      s[4] += xa[j]*w1.x; s[5] += xa[j]*w1.y; s[6] += xa[j]*w1.z; s[7] += xa[j]*w1.w;
    }
#pragma unroll
    for (int off = 32; off > 0; off >>= 1) {
      ss += __shfl_down(ss, off);
#pragma unroll
      for (int e = 0; e < 8; ++e) s[e] += __shfl_down(s[e], off);
    }
    const int wv = tid >> 6, lane = tid & 63;
    if (lane == 0) { red[wv][8] = ss;
#pragma unroll
      for (int e = 0; e < 8; ++e) red[wv][e] = s[e]; }
    __syncthreads();
    if (tid == 0) {
      float sum2 = red[0][8] + red[1][8] + red[2][8] + red[3][8];
      invs = rsqrtf(sum2 * (1.0f / D_DIM) + EPS_RMS);
      float sc[8];
#pragma unroll
      for (int e = 0; e < 8; ++e) sc[e] = red[0][e] + red[1][e] + red[2][e] + red[3][e];
      int i0 = 0; float v0 = sc[0];
#pragma unroll
      for (int e = 1; e < 8; ++e) if (sc[e] > v0) { v0 = sc[e]; i0 = e; }
      int i1 = -1; float v1 = -3.0e38f;
#pragma unroll
      for (int e = 0; e < 8; ++e) if (e != i0 && sc[e] > v1) { v1 = sc[e]; i1 = e; }
      float p1 = 1.0f / (1.0f + expf(v0 - v1));
      float p0 = 1.0f - p1;
      topi[2*t] = i0; topi[2*t+1] = i1;
      gatev[2*t] = p0; gatev[2*t+1] = p1;
    }
    __syncthreads();
    const float inv = invs;
    ushort4 o;
    o.x = f2bf(xv.x*inv); o.y = f2bf(xv.y*inv); o.z = f2bf(xv.z*inv); o.w = f2bf(xv.w*inv);
    reinterpret_cast<ushort4*>(xh + (size_t)t * D_DIM)[tid] = o;
  }
}

// ---------------- count: per-chunk register histogram (no atomics) ----------------
__global__ __launch_bounds__(256) void count_kernel(
    const int* __restrict__ topi, int* __restrict__ percnt, int nent)
{
  const int blk = blockIdx.x;
  const int tid = threadIdx.x;
  const int per = (nent + NCHUNK*256 - 1) / (NCHUNK*256);
  const int cbase = blk * 256 * per;
  int c[8];
#pragma unroll
  for (int q = 0; q < 8; ++q) c[q] = 0;
  for (int i = 0; i < per; ++i) {
    const int idx = cbase + tid * per + i;
    if (idx < nent) {
      const int e = topi[idx];
#pragma unroll
      for (int q = 0; q < 8; ++q) c[q] += (e == q) ? 1 : 0;
    }
  }
#pragma unroll
  for (int off = 32; off > 0; off >>= 1)
#pragma unroll
    for (int q = 0; q < 8; ++q) c[q] += __shfl_down(c[q], off);
  __shared__ int red[4][8];
  const int wv = tid >> 6, lane = tid & 63;
  if (lane == 0)
#pragma unroll
    for (int q = 0; q < 8; ++q) red[wv][q] = c[q];
  __syncthreads();
  if (tid < 8) percnt[blk * 8 + tid] = red[0][tid] + red[1][tid] + red[2][tid] + red[3][tid];
}

// ---------------- scatter (scan folded in): chunk-local LDS cursors ----------------
__global__ __launch_bounds__(256) void scatter_kernel(
    const int* __restrict__ topi, const int* __restrict__ percnt,
    int* __restrict__ rowtok, int* __restrict__ slots, int* __restrict__ offs, int nent)
{
  __shared__ int cur[8];
  const int blk = blockIdx.x, tid = threadIdx.x;
  if (tid == 0) {
    int tot[8];
#pragma unroll
    for (int e = 0; e < 8; ++e) {
      tot[e] = 0;
      for (int c = 0; c < NCHUNK; ++c) tot[e] += percnt[c*8 + e];
    }
    int acc = 0, start[8];
#pragma unroll
    for (int e = 0; e < 8; ++e) {
      start[e] = acc;
      if (blk == 0) offs[e] = acc;
      acc += (tot[e] + 255) & ~255;
    }
    if (blk == 0) offs[8] = acc;
    for (int c = 0; c < blk; ++c)
#pragma unroll
      for (int e = 0; e < 8; ++e) start[e] += percnt[c*8 + e];
#pragma unroll
    for (int e = 0; e < 8; ++e) cur[e] = start[e];
  }
  __syncthreads();
  const int per = (nent + NCHUNK*256 - 1) / (NCHUNK*256);
  const int cbase = blk * 256 * per;
  for (int i = 0; i < per; ++i) {
    const int idx = cbase + tid * per + i;
    if (idx < nent) {
      const int e = topi[idx];
      const int pos = atomicAdd(&cur[e], 1);
      rowtok[pos] = idx >> 1;
      slots[idx] = pos;
    }
  }
}

// ---------------- FFN1 grid: [by < MT1] r11-ring GEMM ; [by >= MT1] W3 transpose blocks ----------------
// W3 conv co-scheduled in ffn1's idle memory BW (ffn1: MfmaUtil 34%, HBM 15%).
// W3t needed only by ffn2, which launches after this kernel completes.
__global__ __launch_bounds__(512, 4) void ffn1_kernel(
    const u16* __restrict__ xh, const u16* __restrict__ Wc,
    const float* __restrict__ W3, u16* __restrict__ W3t,
    const float* __restrict__ b1, const float* __restrict__ b2,
    const int* __restrict__ rowtok, const int* __restrict__ offs,
    u16* __restrict__ h, int MT1)
{
  __shared__ __align__(16) u16 smem[36864];   // 72 KB

  const int tid = threadIdx.x;

  if ((int)blockIdx.y >= MT1) {
    // ---- W3 conversion: 2 x (64x64) tiles per 512-thread block ----
    float* ftile = reinterpret_cast<float*>(smem);          // [2][64][65] floats = 33.3 KB
    const int half = tid >> 8;                               // 0..1
    const int t8 = tid & 255;
    const int tx = t8 & 15, ty = t8 >> 4;
    const int tileIdx = ((int)blockIdx.y - MT1) * 64 + (int)blockIdx.x * 2 + half;  // 0..4095
    const int e = tileIdx >> 9;
    const int rem = tileIdx & 511;
    const int cb = (rem & 15) * 64;      // D cols
    const int rb = (rem >> 4) * 64;      // F rows
    float* tl = ftile + half * 64 * 65;
    const float* Wp = W3 + (size_t)e * F_DIM * D_DIM;
#pragma unroll
    for (int rep = 0; rep < 4; ++rep) {
      const int i = ty + rep * 16;
      float4 v = *reinterpret_cast<const float4*>(Wp + (size_t)(rb + i) * D_DIM + cb + tx * 4);
      tl[i*65 + tx*4+0] = v.x; tl[i*65 + tx*4+1] = v.y;
      tl[i*65 + tx*4+2] = v.z; tl[i*65 + tx*4+3] = v.w;
    }
    __syncthreads();
    u16* op = W3t + (size_t)e * D_DIM * F_DIM;
#pragma unroll
    for (int rep = 0; rep < 4; ++rep) {
      const int j = ty + rep * 16;
      ushort4 o;
      o.x = f2bf(tl[(tx*4+0)*65 + j]);
      o.y = f2bf(tl[(tx*4+1)*65 + j]);
      o.z = f2bf(tl[(tx*4+2)*65 + j]);
      o.w = f2bf(tl[(tx*4+3)*65 + j]);
      *reinterpret_cast<ushort4*>(op + (size_t)(cb + j) * F_DIM + rb + tx*4) = o;
    }
    return;
  }

  const int row0 = blockIdx.y * 256;
  if (row0 >= offs[8]) return;
  int e = 0;
#pragma unroll
  for (int i = 1; i < 8; ++i) e += (row0 >= offs[i]) ? 1 : 0;

  const int bx = blockIdx.x;
  const int n0p = bx * 128;
  const int lane = tid & 63;
  const int l15 = lane & 15;
  const int wv = tid >> 6;
  const int wm = wv >> 1;
  const int wn = wv & 1;

  int arow[2];
  const u16* gAp[2];
#pragma unroll
  for (int j = 0; j < 2; ++j) {
    const int i = tid + 512*j;
    const int p = i >> 3;
    const int v = (i & 7) ^ (p & 7);
    arow[j] = 2*p + (v >> 2);
    int tk = rowtok[row0 + arow[j]];
    if (tk < 0) tk = 0;
    gAp[j] = xh + (size_t)tk * D_DIM + (v & 3) * 8;
  }
  const u16* gBp;
  {
    const int i = tid;
    const int p = i >> 3;
    const int v = (i & 7) ^ (p & 7);
    const int brow = 2*p + (v >> 2);
    gBp = Wc + ((size_t)e * (2*F_DIM) + n0p + brow) * D_DIM + (v & 3) * 8;
  }

  const f32x4 zero = {0.f, 0.f, 0.f, 0.f};
  f32x4 acc[4][4];
#pragma unroll
  for (int i = 0; i < 4; ++i)
#pragma unroll
    for (int j = 0; j < 4; ++j) acc[i][j] = zero;

  const int rlane = (((l15 & 1) << 2) + (lane >> 4)) ^ (l15 >> 1);
  const int aoff = (l15 >> 1) * 64 + rlane * 8;
  const int boff = (l15 >> 1) * 64 + rlane * 8;

#define STAGE1(b, k0)                                                       \
  {                                                                         \
    const int base_ = (b) * 12288;                                          \
    async16(gAp[0] + (k0), &smem[base_ + tid*8]);                           \
    async16(gAp[1] + (k0), &smem[base_ + (tid + 512)*8]);                   \
    async16(gBp   + (k0), &smem[base_ + 8192 + tid*8]);                     \
  }

  STAGE1(0, 0);
  STAGE1(1, 32);

  const int NSTEP = D_DIM / 32;
  for (int t = 0; t < NSTEP; ++t) {
    const int bsel = t % 3;
    if (t + 1 < NSTEP) {
      asm volatile("s_waitcnt vmcnt(3)" ::: "memory");
    } else {
      asm volatile("s_waitcnt vmcnt(0)" ::: "memory");
    }
    __builtin_amdgcn_s_barrier();
    if (t + 2 < NSTEP) {
      const int bn = (t + 2) % 3;
      const int kn = (t + 2) * 32;
      STAGE1(bn, kn);
    }
    const int aB = bsel * 12288, bB = aB + 8192;
    bf16x8 af[4], bv[4];
#pragma unroll
    for (int mi = 0; mi < 4; ++mi)
      af[mi] = *(const bf16x8*)(&smem[aB + (wm*32 + mi*8)*64 + aoff]);
#pragma unroll
    for (int ni = 0; ni < 4; ++ni)
      bv[ni] = *(const bf16x8*)(&smem[bB + (wn*32 + ni*8)*64 + boff]);
#pragma unroll
    for (int mi = 0; mi < 4; ++mi)
#pragma unroll
      for (int ni = 0; ni < 4; ++ni)
        acc[mi][ni] = __builtin_amdgcn_mfma_f32_16x16x32_bf16(af[mi], bv[ni], acc[mi][ni], 0, 0, 0);
  }
#undef STAGE1

#pragma unroll
  for (int mi = 0; mi < 4; ++mi) {
    const int rbase = row0 + wm*64 + mi*16 + (lane >> 4)*4;
#pragma unroll
    for (int q = 0; q < 2; ++q) {
      const int rc = bx*64 + wn*32 + q*16 + l15;
      const float bb1 = b1[e*F_DIM + rc], bb2 = b2[e*F_DIM + rc];
#pragma unroll
      for (int r = 0; r < 4; ++r) {
        float a = acc[mi][2*q][r] + bb1;
        float g = acc[mi][2*q+1][r] + bb2;
        h[(size_t)(rbase + r) * F_DIM + rc] = f2bf(a / (1.f + __expf(-a)) * g);
      }
    }
  }
}

// ---------------- FFN2: round-15 version (2-buf, BK=64, XOR swizzle, XCD chunking) ----------------
__global__ __launch_bounds__(256, 2) void ffn2_kernel(
    const u16* __restrict__ h, const u16* __restrict__ W3t,
    const float* __restrict__ b3, const int* __restrict__ offs,
    float* __restrict__ opart)
{
  __shared__ __align__(16) u16 smem[32768];

  const int lin = blockIdx.y * gridDim.x + blockIdx.x;
  const int qc  = (gridDim.x * gridDim.y) >> 3;
  const int L   = (lin & 7) * qc + (lin >> 3);
  const int bx  = L % gridDim.x;
  const int by  = L / gridDim.x;

  const int row0 = by * 128;
  if (row0 >= offs[8]) return;
  int e = 0;
#pragma unroll
  for (int i = 1; i < 8; ++i) e += (row0 >= offs[i]) ? 1 : 0;

  const int n0 = bx * 128;
  const int tid = threadIdx.x;
  const int lane = tid & 63;
  const int wv = tid >> 6;
  const int wm = wv >> 1;
  const int wn = wv & 1;

  const int srow = tid >> 3;
  const int sseg = (tid & 7) ^ (srow & 7);
  const u16* gA[4]; const u16* gB[4];
#pragma unroll
  for (int j = 0; j < 4; ++j) {
    gA[j] = h   + (size_t)(row0 + srow + 32*j) * F_DIM + sseg * 8;
    gB[j] = W3t + ((size_t)e * D_DIM + n0 + srow + 32*j) * F_DIM + sseg * 8;
  }

  const f32x4 zero = {0.f, 0.f, 0.f, 0.f};
  f32x4 acc[4][4];
#pragma unroll
  for (int i = 0; i < 4; ++i)
#pragma unroll
    for (int j = 0; j < 4; ++j) acc[i][j] = zero;

  const int rswz = (lane & 7) << 3;
  const int kpart = (lane >> 4) * 8;
  const int arowbase = (wm*64 + (lane & 15)) * 64;
  const int browbase = (wn*64 + (lane & 15)) * 64;

#define STAGE2(b, k0)                                                       \
  {                                                                         \
    const int aB_ = (b)*8192, bB_ = 16384 + (b)*8192;                       \
    _Pragma("unroll")                                                       \
    for (int j = 0; j < 4; ++j) {                                           \
      async16(gA[j] + (k0), &smem[aB_ + (tid + 256*j)*8]);                  \
      async16(gB[j] + (k0), &smem[bB_ + (tid + 256*j)*8]);                  \
    }                                                                       \
  }

  STAGE2(0, 0);
  __syncthreads();

  int cur = 0;
  for (int t = 0; t < F_DIM/64; ++t) {
    if (t + 1 < F_DIM/64) STAGE2(cur ^ 1, (t+1)*64);
    const int aB = cur*8192, bB = 16384 + cur*8192;
#pragma unroll
    for (int kk = 0; kk < 2; ++kk) {
      const int ko = kk*32 + kpart;
      bf16x8 af[4], bv[4];
#pragma unroll
      for (int mi = 0; mi < 4; ++mi)
        af[mi] = *(const bf16x8*)(&smem[aB + ((arowbase + mi*1024 + ko) ^ rswz)]);
#pragma unroll
      for (int ni = 0; ni < 4; ++ni)
        bv[ni] = *(const bf16x8*)(&smem[bB + ((browbase + ni*1024 + ko) ^ rswz)]);
#pragma unroll
      for (int mi = 0; mi < 4; ++mi)
#pragma unroll
        for (int ni = 0; ni < 4; ++ni)
          acc[mi][ni] = __builtin_amdgcn_mfma_f32_16x16x32_bf16(af[mi], bv[ni], acc[mi][ni], 0, 0, 0);
    }
    __syncthreads();
    cur ^= 1;
  }
#undef STAGE2

#pragma unroll
  for (int mi = 0; mi < 4; ++mi) {
    const int rbase = row0 + wm*64 + mi*16 + (lane >> 4)*4;
#pragma unroll
    for (int ni = 0; ni < 4; ++ni) {
      const int gc = n0 + wn*64 + ni*16 + (lane & 15);
      const float bb = b3[e*D_DIM + gc];
#pragma unroll
      for (int r = 0; r < 4; ++r)
        opart[(size_t)(rbase + r) * D_DIM + gc] = acc[mi][ni][r] + bb;
    }
  }
}

// ---------------- combine: y[t] = w0*opart[s0] + w1*opart[s1] ----------------
__global__ __launch_bounds__(256) void combine_kernel(
    const float* __restrict__ opart, const int* __restrict__ slots,
    const float* __restrict__ gatev, float* __restrict__ y)
{
  const int t = blockIdx.x;
  const int s0 = slots[2*t], s1 = slots[2*t+1];
  const float w0 = gatev[2*t], w1 = gatev[2*t+1];
  const float4 a = reinterpret_cast<const float4*>(opart + (size_t)s0 * D_DIM)[threadIdx.x];
  const float4 b = reinterpret_cast<const float4*>(opart + (size_t)s1 * D_DIM)[threadIdx.x];
  float4 o;
  o.x = w0*a.x + w1*b.x; o.y = w0*a.y + w1*b.y;
  o.z = w0*a.z + w1*b.z; o.w = w0*a.w + w1*b.w;
  reinterpret_cast<float4*>(y + (size_t)t * D_DIM)[threadIdx.x] = o;
}

extern "C" void kernel_launch(void* const* d_in, const int* in_sizes, int n_in,
                              void* d_out, int out_size, void* d_ws, size_t ws_size,
                              hipStream_t stream)
{
  const float* x  = (const float*)d_in[0];
  const float* Wg = (const float*)d_in[1];
  const float* nw = (const float*)d_in[2];
  const float* W1 = (const float*)d_in[3];
  const float* b1 = (const float*)d_in[4];
  const float* W2 = (const float*)d_in[5];
  const float* b2 = (const float*)d_in[6];
  const float* W3 = (const float*)d_in[7];
  const float* b3 = (const float*)d_in[8];
  float* y = (float*)d_out;

  const int T = in_sizes[0] / D_DIM;           // 4096
  const int NENT = T * 2;
  const int RCAP = ((NENT + E_NUM * 255) + 255) & ~255;
  const int MT1 = RCAP / 256;                  // 40
  const int MT2 = RCAP / 128;                  // 80

  char* ws = (char*)d_ws;
  size_t off_ = 0;
  auto take = [&](size_t bytes) { char* p = ws + off_; off_ = (off_ + bytes + 255) & ~(size_t)255; return p; };
  u16* Wc     = (u16*)take((size_t)E_NUM * 2 * F_DIM * D_DIM * 2); // 64 MB } opart aliases
  u16* W3t    = (u16*)take((size_t)E_NUM * D_DIM * F_DIM * 2);     // 16 MB
  u16* xh     = (u16*)take((size_t)T * D_DIM * 2);
  u16* hbuf   = (u16*)take((size_t)RCAP * F_DIM * 2);              // 40 MB
  int* rowtok = (int*)take((size_t)RCAP * 4);
  int* slots  = (int*)take((size_t)NENT * 4);
  int* topi   = (int*)take((size_t)NENT * 4);
  float* gatev= (float*)take((size_t)NENT * 4);
  int* percnt = (int*)take(NCHUNK * 8 * 4);
  int* offs   = (int*)take(64);
  float* opart = (float*)Wc;   // overlaps Wc (dead after ffn1)
  (void)ws_size; (void)n_in; (void)out_size;

  (void)hipMemsetAsync(rowtok, 0xFF, (size_t)RCAP * 4, stream);

  prep_kernel<<<8192 + T, 256, 0, stream>>>(W1, W2, nw, x, Wg, Wc, xh, topi, gatev);
  count_kernel<<<NCHUNK, 256, 0, stream>>>(topi, percnt, NENT);
  scatter_kernel<<<NCHUNK, 256, 0, stream>>>(topi, percnt, rowtok, slots, offs, NENT);

  // ffn1 grid: y in [0,MT1) = GEMM blocks; y in [MT1, MT1+64) = W3 conversion blocks (4096 tiles / 2)
  ffn1_kernel<<<dim3((2*F_DIM)/128, MT1 + 64), 512, 0, stream>>>(
      xh, Wc, W3, W3t, b1, b2, rowtok, offs, hbuf, MT1);
  ffn2_kernel<<<dim3(D_DIM/128, MT2), 256, 0, stream>>>(hbuf, W3t, b3, offs, opart);
  combine_kernel<<<T, 256, 0, stream>>>(opart, slots, gatev, y);
}